// Round 14
// baseline (70.892 us; speedup 1.0000x reference)
//
#include <hip/hip_runtime.h>
#include <hip/hip_fp16.h>
#include <math.h>
#include <stdint.h>

#define FDIM 1024
#define BTOT 16384
#define EDIM 64
#define NFLD 32
#define NPANEL 4            // 4 panels of 256 cols
#define NPAIRS 10           // upper-tri panel pairs

typedef _Float16 half8 __attribute__((ext_vector_type(8)));
typedef __fp16 fp16x2 __attribute__((ext_vector_type(2)));
typedef float f32x4 __attribute__((ext_vector_type(4)));

// single-instruction f32x2 -> packed f16x2 (v_cvt_pkrtz_f16_f32)
__device__ __forceinline__ uint32_t pk2(float a, float b){
  fp16x2 h = __builtin_amdgcn_cvt_pkrtz(a, b);
  return __builtin_bit_cast(uint32_t, h);
}

__device__ __forceinline__ void gload16(const void* g, void* l){
  __builtin_amdgcn_global_load_lds((const __attribute__((address_space(1))) void*)g,
                                   (__attribute__((address_space(3))) void*)l,
                                   16, 0, 0);
}

__device__ __forceinline__ float fget(const float4& v, int i){
  switch (i){ case 0: return v.x; case 1: return v.y; case 2: return v.z; default: return v.w; }
}

// pair index for ti<=tj: (0,0)=0 (0,1)=1 (0,2)=2 (0,3)=3 (1,1)=4 ... (3,3)=9
__device__ __forceinline__ int pairId(int ti, int tj){
  return ti * NPANEL - (ti * (ti + 1)) / 2 + tj;
}

// Xbt chunk-index map: chunk of column `col` (within a panel-row of 256)
// lives at index CMAP(col). Properties: (1) transpose store i covers the
// contiguous span [i*64, i*64+64) (bijective in l) -> 1KB/instr coalesced;
// (2) gram fragment reads land <=2-way per 16-lane phase (bank-free).
__device__ __forceinline__ int CMAP(int col){
  return ((col & 3) << 6) | ((col >> 2) ^ ((col & 3) << 1));
}

// ---------------------------------------------------------------------------
// transpose_kernel: X f32 [16384][1024] -> Xbt fp16 chunks + linear partials.
// 2048 blocks: block = (panel p, 32-row chunk kb). Lane l loads cols
// c0+4l..4l+3 (float4, 1KB/wave/instr); stores 4 chunks at CMAP(4l+i) =
// i*64 + (l^(2i)): contiguous permuted 1KB per instruction (fixes the
// 64-line scatter of rounds 10-13).
// ---------------------------------------------------------------------------
__global__ __launch_bounds__(256) void transpose_kernel(
    const float* __restrict__ X, const float* __restrict__ w,
    uint4* __restrict__ Xbt, float* __restrict__ linp){
  const int t = threadIdx.x;
  const int bx = blockIdx.x;
  const int p  = bx & 3;                 // panel
  const int kb = bx >> 2;                // 0..511 (32-row chunk)
  const int ro = t >> 6;                 // wave = oct within chunk
  const int l  = t & 63;
  const int og = kb * 4 + ro;            // global k-oct
  const int k0 = og * 8;
  const int c0 = p * 256;

  const float4 w4 = *(const float4*)(w + c0 + 4 * l);

  float4 rv[8];
#pragma unroll
  for (int r = 0; r < 8; ++r)
    rv[r] = *(const float4*)(X + (size_t)(k0 + r) * FDIM + c0 + 4 * l);

  uint4* dst = Xbt + ((size_t)p * 2048 + og) * 256;
#pragma unroll
  for (int i = 0; i < 4; ++i){
    uint4 ch;                            // chunk = 8 k's of col c0+4l+i
    ch.x = pk2(fget(rv[0], i), fget(rv[1], i));
    ch.y = pk2(fget(rv[2], i), fget(rv[3], i));
    ch.z = pk2(fget(rv[4], i), fget(rv[5], i));
    ch.w = pk2(fget(rv[6], i), fget(rv[7], i));
    dst[(i << 6) | (l ^ (i << 1))] = ch;  // CMAP(4l+i): contiguous per i
  }

#pragma unroll
  for (int r = 0; r < 8; ++r){
    float lp = rv[r].x * w4.x + rv[r].y * w4.y + rv[r].z * w4.z + rv[r].w * w4.w;
#pragma unroll
    for (int off = 32; off; off >>= 1) lp += __shfl_xor(lp, off, 64);
    if (l == 0) linp[(size_t)p * BTOT + k0 + r] = lp;
  }
}

// ---------------------------------------------------------------------------
// w2_kernel: 1024 blocks, one field pair (a,b) each. In-block bucketing of
// fields, field-pair GEMM-lets with 32-row x 64-col (+4 pad) fp32 LDS tiles,
// storing the gram-ready fp16 Wp layout (strict-upper masking baked in).
// ---------------------------------------------------------------------------
__global__ __launch_bounds__(256) void w2_kernel(
    const float* __restrict__ vs, const int* __restrict__ fields,
    _Float16* __restrict__ Wp){
  __shared__ float Si[32][68];
  __shared__ float Sj[32][68];
  __shared__ int gI[32], gJ[32];
  __shared__ int cnt[NFLD], pos[NFLD], off[NFLD + 1];
  __shared__ int permS[FDIM];
  const int t = threadIdx.x;

  if (t < NFLD) cnt[t] = 0;
  __syncthreads();
#pragma unroll
  for (int r = 0; r < 4; ++r) atomicAdd(&cnt[fields[t + 256 * r]], 1);
  __syncthreads();
  if (t == 0){
    int s = 0;
    for (int i = 0; i < NFLD; ++i){ off[i] = s; s += cnt[i]; }
    off[NFLD] = s;
  }
  __syncthreads();
  if (t < NFLD) pos[t] = off[t];
  __syncthreads();
#pragma unroll
  for (int r = 0; r < 4; ++r){
    const int idx = t + 256 * r;
    const int p = atomicAdd(&pos[fields[idx]], 1);
    permS[p] = idx;
  }
  __syncthreads();

  const int a = blockIdx.x >> 5, b = blockIdx.x & 31;
  const int oa = off[a], na = off[a + 1] - oa;
  const int ob = off[b], nb_ = off[b + 1] - ob;
  if (na == 0 || nb_ == 0) return;
  for (int ia0 = 0; ia0 < na; ia0 += 32){
    const int nac = min(32, na - ia0);
    for (int jb0 = 0; jb0 < nb_; jb0 += 32){
      const int nbc = min(32, nb_ - jb0);
      __syncthreads();
      if (t < 32){
        gI[t] = (t < nac) ? permS[oa + ia0 + t] : 0;
        gJ[t] = (t < nbc) ? permS[ob + jb0 + t] : 0;
      }
      __syncthreads();
#pragma unroll
      for (int rep = 0; rep < 2; ++rep){
        const int lidx = rep * 256 + t;     // 0..511 = 32 rows x 16 float4
        const int r = lidx >> 4, e4 = (lidx & 15) * 4;
        if (r < nac)
          *(float4*)&Si[r][e4] = *(const float4*)(vs + ((size_t)b * FDIM + gI[r]) * EDIM + e4);
        if (r < nbc)
          *(float4*)&Sj[r][e4] = *(const float4*)(vs + ((size_t)a * FDIM + gJ[r]) * EDIM + e4);
      }
      __syncthreads();
      const int jr = t & 31;
      const int ir0 = t >> 5;               // 0..7
      for (int ko = 0; ko * 8 < nac; ++ko){
        const int ir = ko * 8 + ir0;
        if (ir < nac && jr < nbc){
          float dot = 0.f;
#pragma unroll
          for (int e4 = 0; e4 < EDIM; e4 += 4){
            const float4 x = *(const float4*)&Si[ir][e4];
            const float4 y = *(const float4*)&Sj[jr][e4];
            dot += x.x * y.x + x.y * y.y + x.z * y.z + x.w * y.w;
          }
          const int gi = gI[ir], gj = gJ[jr];
          const int pi = gi >> 8, pj = gj >> 8;
          if (pi <= pj){
            const float v = (gj > gi) ? dot : 0.f;
            const int li = gi & 255, lj = gj & 255;
            const int P  = pairId(pi, pj);
            const int w8 = (li >> 7) * 4 + (lj >> 6);
            const int mb = (li >> 4) & 7, r_ = li & 3;
            const int lane = ((li >> 2) & 3) * 16 + (lj & 15);
            const int nbv = (lj >> 4) & 3;
            const size_t o_ = (size_t)(P * 8 + w8) * 8192
                            + (size_t)((mb * 2 + (r_ >> 1)) * 64 + lane) * 8
                            + (r_ & 1) * 4 + nbv;
            Wp[o_] = (_Float16)v;
          }
        }
      }
    }
  }
}

// ---------------------------------------------------------------------------
// gram_kc: 256 blocks (1/CU), one 64-row k-chunk each. Stages the 4-panel
// fp16 slice (128 KB LDS via gload16, linear copy of the CMAP'd layout) and
// computes all 10 panel-pairs from LDS, dotting each P-chunk with Wp
// (register-preloaded). Fragment addressing uses CMAP; per-16-lane-phase
// bank aliasing <=2-way (free). Pair groups gated by counted vmcnt
// (12/8/4/0) + s_barrier. Diagonal pairs skip the 2 all-zero-W waves.
// ---------------------------------------------------------------------------
__global__ __launch_bounds__(512, 1) void gram_kc(
    const uint4* __restrict__ Xbt, const _Float16* __restrict__ Wp,
    float* __restrict__ partial){
  __shared__ uint4 lds4[8192];   // [oct(8)][panel(4)][chunk(256) CMAP'd]
  const int t = threadIdx.x, w = t >> 6, lane = t & 63;
  const int orow = lane >> 4, rl = lane & 15;
  const int wr = w >> 2, wc = w & 3;     // wave sub-tile (2 x 4) of 256x256
  const int b8 = blockIdx.x * 8;         // first k-oct of this chunk

  // issue all staging, panel-major (4 loads per thread per panel)
#pragma unroll
  for (int p = 0; p < NPANEL; ++p)
#pragma unroll
    for (int q = 0; q < 4; ++q){
      const int m = q * 512 + t;
      const int o = m >> 8, c = m & 255;
      gload16(Xbt + ((size_t)p * 2048 + b8 + o) * 256 + c,
              lds4 + o * 1024 + p * 256 + c);
    }

  // precomputed CMAP'd fragment chunk slots
  int swA[8], swB[4];
#pragma unroll
  for (int mb = 0; mb < 8; ++mb) swA[mb] = CMAP(wr * 128 + mb * 16 + rl);
#pragma unroll
  for (int nb = 0; nb < 4; ++nb) swB[nb] = CMAP(wc * 64 + nb * 16 + rl);

  float wsum = 0.f;

  auto loadB = [&](int tj, half8 (&bf)[2][4]){
#pragma unroll
    for (int s = 0; s < 2; ++s)
#pragma unroll
      for (int nb = 0; nb < 4; ++nb)
        bf[s][nb] = __builtin_bit_cast(half8,
            lds4[(s * 4 + orow) * 1024 + tj * 256 + swB[nb]]);
  };

  auto body = [&](int ti, int tj, const half8 (&bf)[2][4]){
    // diagonal pairs: this wave's whole 128x64 W-subtile is zero -> skip
    if (ti == tj && wr == 1 && wc < 2) return;

    // preload the pair/wave Wp subtile (16 coalesced b128) BEFORE the MFMAs
    const uint4* wp = (const uint4*)(Wp + (size_t)(pairId(ti, tj) * 8 + w) * 8192);
    half8 wreg[16];
#pragma unroll
    for (int q = 0; q < 16; ++q)
      wreg[q] = __builtin_bit_cast(half8, wp[q * 64 + lane]);

    f32x4 acc[8][4];
#pragma unroll
    for (int i = 0; i < 8; ++i)
#pragma unroll
      for (int j = 0; j < 4; ++j) acc[i][j] = {0.f, 0.f, 0.f, 0.f};
#pragma unroll
    for (int s = 0; s < 2; ++s)
#pragma unroll
      for (int mb = 0; mb < 8; ++mb){
        const half8 af = __builtin_bit_cast(half8,
            lds4[(s * 4 + orow) * 1024 + ti * 256 + swA[mb]]);
#pragma unroll
        for (int nb = 0; nb < 4; ++nb)
          acc[mb][nb] = __builtin_amdgcn_mfma_f32_16x16x32_f16(
              af, bf[s][nb], acc[mb][nb], 0, 0, 0);
      }
    // W-dot from registers
#pragma unroll
    for (int mb = 0; mb < 8; ++mb)
#pragma unroll
      for (int h = 0; h < 2; ++h){
        const half8 hv = wreg[mb * 2 + h];
#pragma unroll
        for (int r2 = 0; r2 < 2; ++r2)
#pragma unroll
          for (int nb = 0; nb < 4; ++nb)
            wsum += (float)hv[r2 * 4 + nb] * acc[mb][nb][2 * h + r2];
      }
  };

#define GRAM_GROUP(G, VM)                                         \
  asm volatile("s_waitcnt vmcnt(" #VM ")" ::: "memory");          \
  __builtin_amdgcn_s_barrier();                                   \
  {                                                               \
    half8 bf[2][4];                                               \
    loadB(G, bf);                                                 \
    _Pragma("unroll 1")                                           \
    for (int ti = 0; ti <= (G); ++ti) body(ti, (G), bf);          \
  }

  GRAM_GROUP(0, 12)
  GRAM_GROUP(1, 8)
  GRAM_GROUP(2, 4)
  GRAM_GROUP(3, 0)
#undef GRAM_GROUP

  // block reduce: wave-reduce, then cross-wave via LDS (reuse, post-barrier)
#pragma unroll
  for (int off = 32; off; off >>= 1) wsum += __shfl_xor(wsum, off, 64);
  __syncthreads();
  float* red = (float*)lds4;
  if (lane == 0) red[w] = wsum;
  __syncthreads();
  if (t == 0){
    float s = 0.f;
#pragma unroll
    for (int i = 0; i < 8; ++i) s += red[i];
    partial[blockIdx.x] = s;
  }
}

// ---------------------------------------------------------------------------
// final_out: reduce 256 per-block gram partials (redundantly per block,
// L2-hot), add 4 linear partials per row, sigmoid.
// ---------------------------------------------------------------------------
__global__ __launch_bounds__(256) void final_out(
    const float* __restrict__ partial, const float* __restrict__ linp,
    const float* __restrict__ wb, float* __restrict__ out){
  __shared__ float red[256];
  const int t = threadIdx.x;
  red[t] = partial[t];
  __syncthreads();
  for (int off = 128; off; off >>= 1){
    if (t < off) red[t] += red[t + off];
    __syncthreads();
  }
  const float stot = red[0] + wb[0];
  const int i = blockIdx.x * 256 + t;
  float z = stot;
#pragma unroll
  for (int p = 0; p < NPANEL; ++p) z += linp[(size_t)p * BTOT + i];
  out[i] = 1.f / (1.f + expf(-z));
}

// ---------------------------------------------------------------------------
extern "C" void kernel_launch(void* const* d_in, const int* in_sizes, int n_in,
                              void* d_out, int out_size, void* d_ws,
                              size_t ws_size, hipStream_t stream) {
  const float* X      = (const float*)d_in[0];  // [B, F]
  const int* fields   = (const int*)d_in[1];    // [F]
  const float* ww     = (const float*)d_in[2];  // [1, F]
  const float* wbias  = (const float*)d_in[3];  // [1]
  const float* vs     = (const float*)d_in[4];  // [NF, F, E]
  float* out          = (float*)d_out;          // [B, 1]

  char* ws = (char*)d_ws;
  float* partial = (float*)ws;                        // 256 floats
  float* linp = (float*)(ws + (64 << 10));            // 4*16384 f32 = 256 KB
  _Float16* Wp = (_Float16*)(ws + (size_t)(4 << 20)); // 1.25 MB at 4 MB
  uint4* Xbt = (uint4*)(ws + (size_t)(8 << 20));      // 32 MB at 8 MB offset

  // every cell of partial/linp/Wp/Xbt is written before read: no memset needed

  transpose_kernel<<<2048, 256, 0, stream>>>(X, ww, Xbt, linp);
  w2_kernel<<<NFLD * NFLD, 256, 0, stream>>>(vs, fields, Wp);
  gram_kc<<<256, 512, 0, stream>>>(Xbt, Wp, partial);
  final_out<<<BTOT / 256, 256, 0, stream>>>(partial, linp, wbias, out);
}

// Round 15
// 61.252 us; speedup vs baseline: 1.1574x; 1.1574x over previous
//
#include <hip/hip_runtime.h>
#include <hip/hip_fp16.h>
#include <math.h>
#include <stdint.h>

#define FDIM 1024
#define BTOT 16384
#define EDIM 64
#define NFLD 32
#define NPANEL 4            // 4 panels of 256 cols
#define NPAIRS 10           // upper-tri panel pairs

typedef _Float16 half8 __attribute__((ext_vector_type(8)));
typedef __fp16 fp16x2 __attribute__((ext_vector_type(2)));
typedef float f32x4 __attribute__((ext_vector_type(4)));

// single-instruction f32x2 -> packed f16x2 (v_cvt_pkrtz_f16_f32)
__device__ __forceinline__ uint32_t pk2(float a, float b){
  fp16x2 h = __builtin_amdgcn_cvt_pkrtz(a, b);
  return __builtin_bit_cast(uint32_t, h);
}

__device__ __forceinline__ float fget(const float4& v, int i){
  switch (i){ case 0: return v.x; case 1: return v.y; case 2: return v.z; default: return v.w; }
}

// pair index for ti<=tj: (0,0)=0 (0,1)=1 (0,2)=2 (0,3)=3 (1,1)=4 ... (3,3)=9
__device__ __forceinline__ int pairId(int ti, int tj){
  return ti * NPANEL - (ti * (ti + 1)) / 2 + tj;
}

// LDS chunk-index map within a panel row of 256 chunks. Store side:
// CMAP(4l+i) = (i<<6) | (l^(2i)) -> the i-th ds_write of lane l lands in a
// contiguous permuted 64-chunk span (<=2-way bank aliasing per 16-lane
// phase). Read side uses the same map (both-sides rule; plain ds ops, no
// global_load_lds involved).
__device__ __forceinline__ int CMAP(int col){
  return ((col & 3) << 6) | ((col >> 2) ^ ((col & 3) << 1));
}

// ---------------------------------------------------------------------------
// w2_kernel: 1024 blocks, one field pair (a,b) each. In-block bucketing of
// fields, field-pair GEMM-lets with 32-row x 64-col (+4 pad) fp32 LDS tiles,
// storing the gram-ready fp16 Wp layout (strict-upper masking baked in).
// ---------------------------------------------------------------------------
__global__ __launch_bounds__(256) void w2_kernel(
    const float* __restrict__ vs, const int* __restrict__ fields,
    _Float16* __restrict__ Wp){
  __shared__ float Si[32][68];
  __shared__ float Sj[32][68];
  __shared__ int gI[32], gJ[32];
  __shared__ int cnt[NFLD], pos[NFLD], off[NFLD + 1];
  __shared__ int permS[FDIM];
  const int t = threadIdx.x;

  if (t < NFLD) cnt[t] = 0;
  __syncthreads();
#pragma unroll
  for (int r = 0; r < 4; ++r) atomicAdd(&cnt[fields[t + 256 * r]], 1);
  __syncthreads();
  if (t == 0){
    int s = 0;
    for (int i = 0; i < NFLD; ++i){ off[i] = s; s += cnt[i]; }
    off[NFLD] = s;
  }
  __syncthreads();
  if (t < NFLD) pos[t] = off[t];
  __syncthreads();
#pragma unroll
  for (int r = 0; r < 4; ++r){
    const int idx = t + 256 * r;
    const int p = atomicAdd(&pos[fields[idx]], 1);
    permS[p] = idx;
  }
  __syncthreads();

  const int a = blockIdx.x >> 5, b = blockIdx.x & 31;
  const int oa = off[a], na = off[a + 1] - oa;
  const int ob = off[b], nb_ = off[b + 1] - ob;
  if (na == 0 || nb_ == 0) return;
  for (int ia0 = 0; ia0 < na; ia0 += 32){
    const int nac = min(32, na - ia0);
    for (int jb0 = 0; jb0 < nb_; jb0 += 32){
      const int nbc = min(32, nb_ - jb0);
      __syncthreads();
      if (t < 32){
        gI[t] = (t < nac) ? permS[oa + ia0 + t] : 0;
        gJ[t] = (t < nbc) ? permS[ob + jb0 + t] : 0;
      }
      __syncthreads();
#pragma unroll
      for (int rep = 0; rep < 2; ++rep){
        const int lidx = rep * 256 + t;     // 0..511 = 32 rows x 16 float4
        const int r = lidx >> 4, e4 = (lidx & 15) * 4;
        if (r < nac)
          *(float4*)&Si[r][e4] = *(const float4*)(vs + ((size_t)b * FDIM + gI[r]) * EDIM + e4);
        if (r < nbc)
          *(float4*)&Sj[r][e4] = *(const float4*)(vs + ((size_t)a * FDIM + gJ[r]) * EDIM + e4);
      }
      __syncthreads();
      const int jr = t & 31;
      const int ir0 = t >> 5;               // 0..7
      for (int ko = 0; ko * 8 < nac; ++ko){
        const int ir = ko * 8 + ir0;
        if (ir < nac && jr < nbc){
          float dot = 0.f;
#pragma unroll
          for (int e4 = 0; e4 < EDIM; e4 += 4){
            const float4 x = *(const float4*)&Si[ir][e4];
            const float4 y = *(const float4*)&Sj[jr][e4];
            dot += x.x * y.x + x.y * y.y + x.z * y.z + x.w * y.w;
          }
          const int gi = gI[ir], gj = gJ[jr];
          const int pi = gi >> 8, pj = gj >> 8;
          if (pi <= pj){
            const float v = (gj > gi) ? dot : 0.f;
            const int li = gi & 255, lj = gj & 255;
            const int P  = pairId(pi, pj);
            const int w8 = (li >> 7) * 4 + (lj >> 6);
            const int mb = (li >> 4) & 7, r_ = li & 3;
            const int lane = ((li >> 2) & 3) * 16 + (lj & 15);
            const int nbv = (lj >> 4) & 3;
            const size_t o_ = (size_t)(P * 8 + w8) * 8192
                            + (size_t)((mb * 2 + (r_ >> 1)) * 64 + lane) * 8
                            + (r_ & 1) * 4 + nbv;
            Wp[o_] = (_Float16)v;
          }
        }
      }
    }
  }
}

// ---------------------------------------------------------------------------
// gram_fx: fused transpose + linear + gram. 256 blocks (1/CU), each owns ONE
// 64-row k-chunk of X. Phase 1 (staging): each wave reads its own 8 rows of
// X directly from HBM (f32, exactly once grid-wide: 64 MB — the 96 MB Xbt
// round-trip kernel is DELETED), converts to fp16 chunks in registers,
// ds_writes the CMAP'd [oct][panel][chunk] slice, and accumulates the exact
// f32 linear dot, reduced and stored per row. Staging registers die before
// phase 2 (round-12's spill trap avoided by strict phase separation).
// Phase 2 (compute): one __syncthreads, then the byte-identical round-14
// pair loop: all 10 panel-pairs from LDS, Wp subtile register-preloaded per
// body, diagonal pairs skip the 2 all-zero-W waves. No vmcnt gates needed —
// LDS is read-only after the barrier.
// ---------------------------------------------------------------------------
__global__ __launch_bounds__(512, 1) void gram_fx(
    const float* __restrict__ X, const float* __restrict__ w,
    const _Float16* __restrict__ Wp,
    float* __restrict__ partial, float* __restrict__ lin){
  __shared__ uint4 lds4[8192];   // [oct(8)][panel(4)][chunk(256) CMAP'd]
  const int t = threadIdx.x, wv = t >> 6, lane = t & 63;
  const int orow = lane >> 4, rl = lane & 15;
  const int wr = wv >> 2, wc = wv & 3;     // wave sub-tile (2 x 4) of 256x256
  const int k0 = blockIdx.x * 64 + wv * 8; // this wave's 8 rows (= its oct)

  // ---------------- phase 1: stage + linear ----------------
  float lp[8];
#pragma unroll
  for (int r = 0; r < 8; ++r) lp[r] = 0.f;

#pragma unroll 1
  for (int p = 0; p < NPANEL; ++p){
    const int c0 = p * 256;
    float4 rv[8];
#pragma unroll
    for (int r = 0; r < 8; ++r)
      rv[r] = *(const float4*)(X + (size_t)(k0 + r) * FDIM + c0 + 4 * lane);
    const float4 w4 = *(const float4*)(w + c0 + 4 * lane);
#pragma unroll
    for (int r = 0; r < 8; ++r)
      lp[r] += rv[r].x * w4.x + rv[r].y * w4.y + rv[r].z * w4.z + rv[r].w * w4.w;

    uint4* base = lds4 + wv * 1024 + p * 256;
#pragma unroll
    for (int i = 0; i < 4; ++i){
      uint4 ch;                            // chunk = 8 k's of col c0+4*lane+i
      ch.x = pk2(fget(rv[0], i), fget(rv[1], i));
      ch.y = pk2(fget(rv[2], i), fget(rv[3], i));
      ch.z = pk2(fget(rv[4], i), fget(rv[5], i));
      ch.w = pk2(fget(rv[6], i), fget(rv[7], i));
      base[(i << 6) | (lane ^ (i << 1))] = ch;   // CMAP(4*lane+i)
    }
  }

  // exact-f32 linear term for this wave's 8 rows
#pragma unroll
  for (int r = 0; r < 8; ++r){
    float v = lp[r];
#pragma unroll
    for (int off = 32; off; off >>= 1) v += __shfl_xor(v, off, 64);
    if (lane == 0) lin[k0 + r] = v;
  }

  __syncthreads();   // all waves' ds_writes visible; LDS read-only below

  // ---------------- phase 2: pair loop (round-14 body) ----------------
  int swA[8], swB[4];
#pragma unroll
  for (int mb = 0; mb < 8; ++mb) swA[mb] = CMAP(wr * 128 + mb * 16 + rl);
#pragma unroll
  for (int nb = 0; nb < 4; ++nb) swB[nb] = CMAP(wc * 64 + nb * 16 + rl);

  float wsum = 0.f;

  auto loadB = [&](int tj, half8 (&bf)[2][4]){
#pragma unroll
    for (int s = 0; s < 2; ++s)
#pragma unroll
      for (int nb = 0; nb < 4; ++nb)
        bf[s][nb] = __builtin_bit_cast(half8,
            lds4[(s * 4 + orow) * 1024 + tj * 256 + swB[nb]]);
  };

  auto body = [&](int ti, int tj, const half8 (&bf)[2][4]){
    // diagonal pairs: this wave's whole 128x64 W-subtile is zero -> skip
    if (ti == tj && wr == 1 && wc < 2) return;

    // preload the pair/wave Wp subtile (16 coalesced b128) BEFORE the MFMAs
    const uint4* wp = (const uint4*)(Wp + (size_t)(pairId(ti, tj) * 8 + wv) * 8192);
    half8 wreg[16];
#pragma unroll
    for (int q = 0; q < 16; ++q)
      wreg[q] = __builtin_bit_cast(half8, wp[q * 64 + lane]);

    f32x4 acc[8][4];
#pragma unroll
    for (int i = 0; i < 8; ++i)
#pragma unroll
      for (int j = 0; j < 4; ++j) acc[i][j] = {0.f, 0.f, 0.f, 0.f};
#pragma unroll
    for (int s = 0; s < 2; ++s)
#pragma unroll
      for (int mb = 0; mb < 8; ++mb){
        const half8 af = __builtin_bit_cast(half8,
            lds4[(s * 4 + orow) * 1024 + ti * 256 + swA[mb]]);
#pragma unroll
        for (int nb = 0; nb < 4; ++nb)
          acc[mb][nb] = __builtin_amdgcn_mfma_f32_16x16x32_f16(
              af, bf[s][nb], acc[mb][nb], 0, 0, 0);
      }
    // W-dot from registers
#pragma unroll
    for (int mb = 0; mb < 8; ++mb)
#pragma unroll
      for (int h = 0; h < 2; ++h){
        const half8 hv = wreg[mb * 2 + h];
#pragma unroll
        for (int r2 = 0; r2 < 2; ++r2)
#pragma unroll
          for (int nb = 0; nb < 4; ++nb)
            wsum += (float)hv[r2 * 4 + nb] * acc[mb][nb][2 * h + r2];
      }
  };

#pragma unroll 1
  for (int G = 0; G < NPANEL; ++G){
    half8 bf[2][4];
    loadB(G, bf);
#pragma unroll 1
    for (int ti = 0; ti <= G; ++ti) body(ti, G, bf);
  }

  // block reduce: wave-reduce, then cross-wave via LDS (reuse, post-barrier)
#pragma unroll
  for (int off = 32; off; off >>= 1) wsum += __shfl_xor(wsum, off, 64);
  __syncthreads();
  float* red = (float*)lds4;
  if (lane == 0) red[wv] = wsum;
  __syncthreads();
  if (t == 0){
    float s = 0.f;
#pragma unroll
    for (int i = 0; i < 8; ++i) s += red[i];
    partial[blockIdx.x] = s;
  }
}

// ---------------------------------------------------------------------------
// final_out: reduce 256 per-block gram partials (redundantly per block,
// L2-hot), add the complete linear value, sigmoid.
// ---------------------------------------------------------------------------
__global__ __launch_bounds__(256) void final_out(
    const float* __restrict__ partial, const float* __restrict__ lin,
    const float* __restrict__ wb, float* __restrict__ out){
  __shared__ float red[256];
  const int t = threadIdx.x;
  red[t] = partial[t];
  __syncthreads();
  for (int off = 128; off; off >>= 1){
    if (t < off) red[t] += red[t + off];
    __syncthreads();
  }
  const float stot = red[0] + wb[0];
  const int i = blockIdx.x * 256 + t;
  const float z = lin[i] + stot;
  out[i] = 1.f / (1.f + expf(-z));
}

// ---------------------------------------------------------------------------
extern "C" void kernel_launch(void* const* d_in, const int* in_sizes, int n_in,
                              void* d_out, int out_size, void* d_ws,
                              size_t ws_size, hipStream_t stream) {
  const float* X      = (const float*)d_in[0];  // [B, F]
  const int* fields   = (const int*)d_in[1];    // [F]
  const float* ww     = (const float*)d_in[2];  // [1, F]
  const float* wbias  = (const float*)d_in[3];  // [1]
  const float* vs     = (const float*)d_in[4];  // [NF, F, E]
  float* out          = (float*)d_out;          // [B, 1]

  char* ws = (char*)d_ws;
  float* partial = (float*)ws;                        // 256 floats
  float* lin = (float*)(ws + (64 << 10));             // 16384 f32 = 64 KB
  _Float16* Wp = (_Float16*)(ws + (size_t)(4 << 20)); // 1.25 MB at 4 MB

  // every cell of partial/lin/Wp is written before read: no memset needed

  w2_kernel<<<NFLD * NFLD, 256, 0, stream>>>(vs, fields, Wp);
  gram_fx<<<256, 512, 0, stream>>>(X, ww, Wp, partial, lin);
  final_out<<<BTOT / 256, 256, 0, stream>>>(partial, lin, wbias, out);
}